// Round 1
// baseline (1495.683 us; speedup 1.0000x reference)
//
#include <hip/hip_runtime.h>
#include <hip/hip_bf16.h>
#include <hip/hip_fp16.h>

#define T_SEQ 2048
#define D_MODEL 1024
#define NB 2
#define NH 16
#define HD 64

using f16x8 = __attribute__((ext_vector_type(8))) _Float16;
using f16x4 = __attribute__((ext_vector_type(4))) _Float16;
using f32x4 = __attribute__((ext_vector_type(4))) float;
using s16x8 = __attribute__((ext_vector_type(8))) short;

// ---------------- init: zero absmax accumulators ----------------
__global__ void k_init(unsigned int* amax) {
    if (threadIdx.x < 8) amax[threadIdx.x] = 0u;
}

// ---------------- absmax reduction (float4 grid-stride) ----------------
__global__ void k_absmax(const float* __restrict__ p, long n4, unsigned int* __restrict__ amax) {
    long i0 = (long)blockIdx.x * blockDim.x + threadIdx.x;
    long stride = (long)gridDim.x * blockDim.x;
    float m = 0.f;
    for (long i = i0; i < n4; i += stride) {
        float4 v = ((const float4*)p)[i];
        m = fmaxf(m, fmaxf(fmaxf(fabsf(v.x), fabsf(v.y)), fmaxf(fabsf(v.z), fabsf(v.w))));
    }
    #pragma unroll
    for (int off = 32; off; off >>= 1) m = fmaxf(m, __shfl_xor(m, off));
    if ((threadIdx.x & 63) == 0 && m > 0.f)
        atomicMax(amax, __float_as_uint(m));   // valid: non-negative floats order as uints
}

// ---------------- quantize to integer codes stored as f16 ----------------
__global__ void k_quant(const float* __restrict__ in, _Float16* __restrict__ out,
                        const unsigned int* __restrict__ amax, long n4) {
    // scale exactly as reference: max(max_abs/127, 1e-8); true division + rintf (half-even)
    float scale = fmaxf(__uint_as_float(*amax) / 127.0f, 1e-8f);
    long i0 = (long)blockIdx.x * blockDim.x + threadIdx.x;
    long stride = (long)gridDim.x * blockDim.x;
    for (long i = i0; i < n4; i += stride) {
        float4 v = ((const float4*)in)[i];
        f16x4 o;
        o[0] = (_Float16)fminf(127.f, fmaxf(-128.f, rintf(v.x / scale)));
        o[1] = (_Float16)fminf(127.f, fmaxf(-128.f, rintf(v.y / scale)));
        o[2] = (_Float16)fminf(127.f, fmaxf(-128.f, rintf(v.z / scale)));
        o[3] = (_Float16)fminf(127.f, fmaxf(-128.f, rintf(v.w / scale)));
        ((f16x4*)out)[i] = o;
    }
}

// ---------------- GEMM: C[M=4096][N=1024] = (A q-codes) @ (W q-codes)^T * sA*sB + bias ----------------
// A: [4096][1024] f16 codes, W: [1024][1024] f16 codes (row-major, K contiguous -> B^T GEMM)
// OUTMODE 0: out[row*1024+col]  (standard [B*T, D])
// OUTMODE 1: scatter to [B, H, T, Hd] for attention
template <int OUTMODE>
__global__ __launch_bounds__(256)
void k_gemm(const _Float16* __restrict__ A, const _Float16* __restrict__ Bw,
            const float* __restrict__ bias,
            const unsigned int* __restrict__ amaxA, const unsigned int* __restrict__ amaxB,
            float* __restrict__ out) {
    __shared__ _Float16 Asm[128][40];   // pad 32->40: 16B-aligned rows, 2-way banks (free)
    __shared__ _Float16 Bsm[128][40];

    const int tid = threadIdx.x;
    const int m0 = blockIdx.y * 128;
    const int n0 = blockIdx.x * 128;
    const int wid = tid >> 6, lane = tid & 63;
    const int wr = wid >> 1, wc = wid & 1;

    f32x4 acc[4][4];
    #pragma unroll
    for (int m = 0; m < 4; ++m)
        #pragma unroll
        for (int n = 0; n < 4; ++n)
            acc[m][n] = (f32x4){0.f, 0.f, 0.f, 0.f};

    for (int kt = 0; kt < 1024; kt += 32) {
        __syncthreads();
        #pragma unroll
        for (int c = 0; c < 2; ++c) {
            int id = tid + c * 256;       // 0..511
            int row = id >> 2;            // 128 rows, 4 chunks of 8 halves each
            int col = (id & 3) * 8;
            *(s16x8*)&Asm[row][col] = *(const s16x8*)&A[(long)(m0 + row) * 1024 + kt + col];
            *(s16x8*)&Bsm[row][col] = *(const s16x8*)&Bw[(long)(n0 + row) * 1024 + kt + col];
        }
        __syncthreads();
        f16x8 af[4], bf[4];
        #pragma unroll
        for (int m = 0; m < 4; ++m)
            af[m] = *(const f16x8*)&Asm[wr * 64 + m * 16 + (lane & 15)][(lane >> 4) * 8];
        #pragma unroll
        for (int n = 0; n < 4; ++n)
            bf[n] = *(const f16x8*)&Bsm[wc * 64 + n * 16 + (lane & 15)][(lane >> 4) * 8];
        #pragma unroll
        for (int m = 0; m < 4; ++m)
            #pragma unroll
            for (int n = 0; n < 4; ++n)
                acc[m][n] = __builtin_amdgcn_mfma_f32_16x16x32_f16(af[m], bf[n], acc[m][n], 0, 0, 0);
    }

    float sA = fmaxf(__uint_as_float(*amaxA) / 127.0f, 1e-8f);
    float sB = fmaxf(__uint_as_float(*amaxB) / 127.0f, 1e-8f);
    float s = sA * sB;
    #pragma unroll
    for (int m = 0; m < 4; ++m) {
        #pragma unroll
        for (int n = 0; n < 4; ++n) {
            int col = n0 + wc * 64 + n * 16 + (lane & 15);
            float bcol = bias[col];
            #pragma unroll
            for (int r = 0; r < 4; ++r) {
                int row = m0 + wr * 64 + m * 16 + (lane >> 4) * 4 + r;
                float val = acc[m][n][r] * s + bcol;
                if (OUTMODE == 0) {
                    out[(long)row * 1024 + col] = val;
                } else {
                    int b = row >> 11, t = row & 2047;
                    int h = col >> 6, d = col & 63;
                    out[(((long)(b * NH + h)) * T_SEQ + t) * HD + d] = val;
                }
            }
        }
    }
}

// ---------------- causal attention, fp32, online softmax ----------------
// q,k,v: [B*H][T][64] fp32;  y: [B][T][H*64] fp32
__global__ __launch_bounds__(256)
void k_attn(const float* __restrict__ q, const float* __restrict__ k,
            const float* __restrict__ v, float* __restrict__ y) {
    __shared__ float Ksm[64][65];   // stride 65: (j+d)%32 -> 2-way conflict (free)
    __shared__ float Vsm[64][65];
    __shared__ float Qsm[4][64];
    __shared__ float Psm[4][64];

    const int bh = blockIdx.y;          // 0..31
    const int r0 = blockIdx.x * 4;      // 4 query rows per block, 1 per wave
    const int wid = threadIdx.x >> 6;
    const int lane = threadIdx.x & 63;
    const int r = r0 + wid;
    const long base = (long)bh * T_SEQ * HD;

    Qsm[wid][lane] = q[base + (long)r * HD + lane] * 0.125f;   // 1/sqrt(64)

    float mrun = -INFINITY, lrun = 0.f, oacc = 0.f;
    const int ntiles = ((r0 + 3) >> 6) + 1;
    for (int jt = 0; jt < ntiles; ++jt) {
        __syncthreads();
        #pragma unroll
        for (int c = 0; c < 4; ++c) {
            int id = threadIdx.x + c * 256;   // 0..1023 -> 64 rows x 16 float4
            int row = id >> 4;
            int col = (id & 15) * 4;
            float4 kv = *(const float4*)&k[base + (long)(jt * 64 + row) * HD + col];
            Ksm[row][col + 0] = kv.x; Ksm[row][col + 1] = kv.y;
            Ksm[row][col + 2] = kv.z; Ksm[row][col + 3] = kv.w;
            float4 vv = *(const float4*)&v[base + (long)(jt * 64 + row) * HD + col];
            Vsm[row][col + 0] = vv.x; Vsm[row][col + 1] = vv.y;
            Vsm[row][col + 2] = vv.z; Vsm[row][col + 3] = vv.w;
        }
        __syncthreads();
        if (jt * 64 <= r) {
            float s = 0.f;
            #pragma unroll 16
            for (int d = 0; d < 64; ++d) s += Qsm[wid][d] * Ksm[lane][d];
            int jg = jt * 64 + lane;
            s = (jg <= r) ? s : -INFINITY;
            float tmax = s;
            #pragma unroll
            for (int off = 32; off; off >>= 1) tmax = fmaxf(tmax, __shfl_xor(tmax, off));
            float mnew = fmaxf(mrun, tmax);
            float corr = __expf(mrun - mnew);   // exp(-inf)=0 on first tile
            float p = __expf(s - mnew);         // masked lanes: exp(-inf)=0
            float psum = p;
            #pragma unroll
            for (int off = 32; off; off >>= 1) psum += __shfl_xor(psum, off);
            lrun = lrun * corr + psum;
            Psm[wid][lane] = p;
            float pv = 0.f;
            #pragma unroll 16
            for (int j = 0; j < 64; ++j) pv += Psm[wid][j] * Vsm[j][lane];
            oacc = oacc * corr + pv;
            mrun = mnew;
        }
    }
    int b = bh >> 4, h = bh & 15;
    y[((long)(b * T_SEQ + r)) * D_MODEL + h * HD + lane] = oacc / lrun;
}

// ---------------- launch ----------------
extern "C" void kernel_launch(void* const* d_in, const int* in_sizes, int n_in,
                              void* d_out, int out_size, void* d_ws, size_t ws_size,
                              hipStream_t stream) {
    const float* x  = (const float*)d_in[0];
    const float* Wq = (const float*)d_in[1];
    const float* bq = (const float*)d_in[2];
    const float* Wk = (const float*)d_in[3];
    const float* bk = (const float*)d_in[4];
    const float* Wv = (const float*)d_in[5];
    const float* bv = (const float*)d_in[6];
    const float* Wo = (const float*)d_in[7];
    const float* bo = (const float*)d_in[8];
    float* out = (float*)d_out;

    char* ws = (char*)d_ws;
    unsigned int* amax = (unsigned int*)ws;                    // 8 slots
    _Float16* xq  = (_Float16*)(ws + 256);                     // 8 MB
    _Float16* wqh = (_Float16*)(ws + 256 + 8388608L);          // 2 MB
    _Float16* wkh = (_Float16*)(ws + 256 + 8388608L + 2097152L);
    _Float16* wvh = (_Float16*)(ws + 256 + 8388608L + 2L * 2097152L);
    _Float16* woh = (_Float16*)(ws + 256 + 8388608L + 3L * 2097152L);
    float* qb = (float*)(ws + 256 + 8388608L + 4L * 2097152L);           // 16 MB
    float* kb = (float*)(ws + 256 + 8388608L + 4L * 2097152L + 16777216L);
    float* vb = (float*)(ws + 256 + 8388608L + 4L * 2097152L + 2L * 16777216L);
    float* yb = (float*)(ws + 256 + 8388608L + 4L * 2097152L + 3L * 16777216L);
    _Float16* yq = (_Float16*)(ws + 256 + 8388608L + 4L * 2097152L + 4L * 16777216L);  // 8 MB

    const long NX4 = (long)NB * T_SEQ * D_MODEL / 4;   // 1048576
    const long NW4 = (long)D_MODEL * D_MODEL / 4;      // 262144

    k_init<<<1, 64, 0, stream>>>(amax);
    k_absmax<<<1024, 256, 0, stream>>>(x,  NX4, amax + 0);
    k_absmax<<<512,  256, 0, stream>>>(Wq, NW4, amax + 1);
    k_absmax<<<512,  256, 0, stream>>>(Wk, NW4, amax + 2);
    k_absmax<<<512,  256, 0, stream>>>(Wv, NW4, amax + 3);
    k_absmax<<<512,  256, 0, stream>>>(Wo, NW4, amax + 4);

    k_quant<<<1024, 256, 0, stream>>>(x,  xq,  amax + 0, NX4);
    k_quant<<<512,  256, 0, stream>>>(Wq, wqh, amax + 1, NW4);
    k_quant<<<512,  256, 0, stream>>>(Wk, wkh, amax + 2, NW4);
    k_quant<<<512,  256, 0, stream>>>(Wv, wvh, amax + 3, NW4);
    k_quant<<<512,  256, 0, stream>>>(Wo, woh, amax + 4, NW4);

    dim3 ggrid(8, 32);
    k_gemm<1><<<ggrid, 256, 0, stream>>>(xq, wqh, bq, amax + 0, amax + 1, qb);
    k_gemm<1><<<ggrid, 256, 0, stream>>>(xq, wkh, bk, amax + 0, amax + 2, kb);
    k_gemm<1><<<ggrid, 256, 0, stream>>>(xq, wvh, bv, amax + 0, amax + 3, vb);

    k_attn<<<dim3(T_SEQ / 4, NB * NH), 256, 0, stream>>>(qb, kb, vb, yb);

    k_absmax<<<1024, 256, 0, stream>>>(yb, NX4, amax + 5);
    k_quant<<<1024, 256, 0, stream>>>(yb, yq, amax + 5, NX4);
    k_gemm<0><<<ggrid, 256, 0, stream>>>(yq, woh, bo, amax + 5, amax + 4, out);
}

// Round 2
// 449.488 us; speedup vs baseline: 3.3275x; 3.3275x over previous
//
#include <hip/hip_runtime.h>
#include <hip/hip_bf16.h>
#include <hip/hip_fp16.h>

#define T_SEQ 2048
#define D_MODEL 1024
#define NB 2
#define NH 16
#define HD 64

using f16x8 = __attribute__((ext_vector_type(8))) _Float16;
using f16x4 = __attribute__((ext_vector_type(4))) _Float16;
using f32x4 = __attribute__((ext_vector_type(4))) float;

__device__ __forceinline__ void gload_lds16(const void* g, void* l) {
    __builtin_amdgcn_global_load_lds((const __attribute__((address_space(1))) void*)g,
                                     (__attribute__((address_space(3))) void*)l, 16, 0, 0);
}

// ---------------- init: zero absmax accumulators ----------------
__global__ void k_init(unsigned int* amax) {
    if (threadIdx.x < 8) amax[threadIdx.x] = 0u;
}

// ---------------- absmax reduction (float4 grid-stride) ----------------
__global__ void k_absmax(const float* __restrict__ p, long n4, unsigned int* __restrict__ amax) {
    long i0 = (long)blockIdx.x * blockDim.x + threadIdx.x;
    long stride = (long)gridDim.x * blockDim.x;
    float m = 0.f;
    for (long i = i0; i < n4; i += stride) {
        float4 v = ((const float4*)p)[i];
        m = fmaxf(m, fmaxf(fmaxf(fabsf(v.x), fabsf(v.y)), fmaxf(fabsf(v.z), fabsf(v.w))));
    }
    #pragma unroll
    for (int off = 32; off; off >>= 1) m = fmaxf(m, __shfl_xor(m, off));
    if ((threadIdx.x & 63) == 0 && m > 0.f)
        atomicMax(amax, __float_as_uint(m));   // valid: non-negative floats order as uints
}

// ---------------- quantize to integer codes stored as f16 ----------------
__global__ void k_quant(const float* __restrict__ in, _Float16* __restrict__ out,
                        const unsigned int* __restrict__ amax, long n4) {
    float scale = fmaxf(__uint_as_float(*amax) / 127.0f, 1e-8f);
    long i0 = (long)blockIdx.x * blockDim.x + threadIdx.x;
    long stride = (long)gridDim.x * blockDim.x;
    for (long i = i0; i < n4; i += stride) {
        float4 v = ((const float4*)in)[i];
        f16x4 o;
        o[0] = (_Float16)fminf(127.f, fmaxf(-128.f, rintf(v.x / scale)));
        o[1] = (_Float16)fminf(127.f, fmaxf(-128.f, rintf(v.y / scale)));
        o[2] = (_Float16)fminf(127.f, fmaxf(-128.f, rintf(v.z / scale)));
        o[3] = (_Float16)fminf(127.f, fmaxf(-128.f, rintf(v.w / scale)));
        ((f16x4*)out)[i] = o;
    }
}

// ---------------- GEMM: C[4096][1024] = (A codes) @ (W codes)^T * sA*sB + bias ----------------
// OUTMODE 0: fp32 out[row*1024+col].  OUTMODE 2: f16 out at [b,h][t][d] = ((b*16+h)*2048+t)*64+d
template <int OUTMODE>
__global__ __launch_bounds__(256)
void k_gemm(const _Float16* __restrict__ A, const _Float16* __restrict__ Bw,
            const float* __restrict__ bias,
            const unsigned int* __restrict__ amaxA, const unsigned int* __restrict__ amaxB,
            void* __restrict__ outv) {
    __shared__ _Float16 Asm[128 * 32];   // linear: global_load_lds dest must be unpadded
    __shared__ _Float16 Bsm[128 * 32];

    const int tid = threadIdx.x;
    const int m0 = blockIdx.y * 128;
    const int n0 = blockIdx.x * 128;
    const int wid = tid >> 6, lane = tid & 63;
    const int r16 = lane & 15, g = lane >> 4;
    const int wr = wid >> 1, wc = wid & 1;

    f32x4 acc[4][4];
    #pragma unroll
    for (int m = 0; m < 4; ++m)
        #pragma unroll
        for (int n = 0; n < 4; ++n)
            acc[m][n] = (f32x4){0.f, 0.f, 0.f, 0.f};

    for (int kt = 0; kt < 1024; kt += 32) {
        __syncthreads();
        #pragma unroll
        for (int s2 = 0; s2 < 2; ++s2) {
            int c = tid + s2 * 256;          // 0..511 chunks of 8 f16 (16B)
            int row = c >> 2, cb = (c & 3) * 8;
            gload_lds16(&A[(long)(m0 + row) * 1024 + kt + cb], &Asm[c * 8]);
            gload_lds16(&Bw[(long)(n0 + row) * 1024 + kt + cb], &Bsm[c * 8]);
        }
        __syncthreads();   // drains vmcnt before barrier
        f16x8 af[4], bf[4];
        #pragma unroll
        for (int m = 0; m < 4; ++m)
            af[m] = *(const f16x8*)&Asm[(wr * 64 + m * 16 + r16) * 32 + g * 8];
        #pragma unroll
        for (int n = 0; n < 4; ++n)
            bf[n] = *(const f16x8*)&Bsm[(wc * 64 + n * 16 + r16) * 32 + g * 8];
        #pragma unroll
        for (int m = 0; m < 4; ++m)
            #pragma unroll
            for (int n = 0; n < 4; ++n)
                acc[m][n] = __builtin_amdgcn_mfma_f32_16x16x32_f16(af[m], bf[n], acc[m][n], 0, 0, 0);
    }

    float sA = fmaxf(__uint_as_float(*amaxA) / 127.0f, 1e-8f);
    float sB = fmaxf(__uint_as_float(*amaxB) / 127.0f, 1e-8f);
    float s = sA * sB;
    #pragma unroll
    for (int m = 0; m < 4; ++m) {
        #pragma unroll
        for (int n = 0; n < 4; ++n) {
            int col = n0 + wc * 64 + n * 16 + r16;
            float bcol = bias[col];
            #pragma unroll
            for (int r = 0; r < 4; ++r) {
                int row = m0 + wr * 64 + m * 16 + g * 4 + r;
                float val = acc[m][n][r] * s + bcol;
                if (OUTMODE == 0) {
                    ((float*)outv)[(long)row * 1024 + col] = val;
                } else {
                    int b = row >> 11, t = row & 2047;
                    int h = col >> 6, d = col & 63;
                    ((_Float16*)outv)[(((long)(b * NH + h)) * T_SEQ + t) * HD + d] = (_Float16)val;
                }
            }
        }
    }
}

// ---------------- V transpose: [bh][t][d] f16 -> [bh][d][t] f16 ----------------
__global__ __launch_bounds__(256)
void k_vtrans(const _Float16* __restrict__ v, _Float16* __restrict__ vt) {
    __shared__ _Float16 sm[64][72];
    const int bh = blockIdx.y, tx = blockIdx.x;
    const int tid = threadIdx.x;
    const long ibase = (long)bh * T_SEQ * HD + (long)tx * 64 * HD;
    #pragma unroll
    for (int s2 = 0; s2 < 2; ++s2) {
        int c = tid + s2 * 256;
        int r = c >> 3, cc = (c & 7) * 8;
        *(f16x8*)&sm[r][cc] = *(const f16x8*)&v[ibase + (long)r * HD + cc];
    }
    __syncthreads();
    #pragma unroll
    for (int s2 = 0; s2 < 2; ++s2) {
        int c = tid + s2 * 256;
        int d = c >> 3, cc = (c & 7) * 8;
        f16x8 o;
        #pragma unroll
        for (int j = 0; j < 8; ++j) o[j] = sm[cc + j][d];
        *(f16x8*)&vt[(long)(bh * HD + d) * T_SEQ + tx * 64 + cc] = o;
    }
}

// ---------------- flash attention, f16 MFMA, online softmax ----------------
// q,k: f16 [bh][t][64]; vt: f16 [bh][64][t]; y: fp32 [B][T][1024]
__global__ __launch_bounds__(256)
void k_attn(const _Float16* __restrict__ q, const _Float16* __restrict__ k,
            const _Float16* __restrict__ vt, float* __restrict__ y) {
    __shared__ _Float16 Ksm[64][72];        // [key][d], pad 72: uniform banks for b128 frags
    __shared__ _Float16 Vsm[64][72];        // [d][key]
    __shared__ _Float16 Psm[4][16][72];     // per-wave P round-trip (C-layout -> A-layout)

    const int bh = blockIdx.y;
    const int bx = (gridDim.x - 1) - blockIdx.x;   // heavy blocks dispatch first
    const int t0 = bx * 64;
    const int tid = threadIdx.x, wid = tid >> 6, lane = tid & 63;
    const int r16 = lane & 15, g = lane >> 4;
    const long base = (long)bh * T_SEQ * HD;
    const long vbase = (long)bh * HD * T_SEQ;

    // Q fragments (A-layout), pre-scaled by 1/sqrt(64)
    f16x8 qf[2];
    {
        const _Float16* qp = q + base + (long)(t0 + wid * 16 + r16) * HD + g * 8;
        qf[0] = *(const f16x8*)qp;
        qf[1] = *(const f16x8*)(qp + 32);
        #pragma unroll
        for (int j = 0; j < 8; ++j) { qf[0][j] *= (_Float16)0.125f; qf[1][j] *= (_Float16)0.125f; }
    }

    float mrun[4], lrun[4];
    f32x4 oacc[4];
    #pragma unroll
    for (int r = 0; r < 4; ++r) { mrun[r] = -INFINITY; lrun[r] = 0.f; }
    #pragma unroll
    for (int nb = 0; nb < 4; ++nb) oacc[nb] = (f32x4){0.f, 0.f, 0.f, 0.f};

    for (int jt = 0; jt <= bx; ++jt) {
        __syncthreads();
        #pragma unroll
        for (int s2 = 0; s2 < 2; ++s2) {
            int c = tid + s2 * 256;
            int row = c >> 3, cc = (c & 7) * 8;
            *(f16x8*)&Ksm[row][cc] = *(const f16x8*)&k[base + (long)(jt * 64 + row) * HD + cc];
            *(f16x8*)&Vsm[row][cc] = *(const f16x8*)&vt[vbase + (long)row * T_SEQ + jt * 64 + cc];
        }
        __syncthreads();

        // S = Q K^T  (4 col-blocks x K=64)
        f32x4 s[4];
        #pragma unroll
        for (int nb = 0; nb < 4; ++nb) {
            f16x8 kb0 = *(const f16x8*)&Ksm[nb * 16 + r16][g * 8];
            f16x8 kb1 = *(const f16x8*)&Ksm[nb * 16 + r16][32 + g * 8];
            f32x4 a = (f32x4){0.f, 0.f, 0.f, 0.f};
            a = __builtin_amdgcn_mfma_f32_16x16x32_f16(qf[0], kb0, a, 0, 0, 0);
            a = __builtin_amdgcn_mfma_f32_16x16x32_f16(qf[1], kb1, a, 0, 0, 0);
            s[nb] = a;
        }

        if (jt == bx) {   // diagonal tile: causal mask
            #pragma unroll
            for (int nb = 0; nb < 4; ++nb)
                #pragma unroll
                for (int r = 0; r < 4; ++r)
                    if (nb * 16 + r16 > wid * 16 + g * 4 + r) s[nb][r] = -INFINITY;
        }

        float p[4][4];
        #pragma unroll
        for (int r = 0; r < 4; ++r) {
            float rmax = fmaxf(fmaxf(s[0][r], s[1][r]), fmaxf(s[2][r], s[3][r]));
            #pragma unroll
            for (int off = 1; off < 16; off <<= 1) rmax = fmaxf(rmax, __shfl_xor(rmax, off));
            float mnew = fmaxf(mrun[r], rmax);
            float corr = __expf(mrun[r] - mnew);
            float psum = 0.f;
            #pragma unroll
            for (int nb = 0; nb < 4; ++nb) { p[nb][r] = __expf(s[nb][r] - mnew); psum += p[nb][r]; }
            #pragma unroll
            for (int off = 1; off < 16; off <<= 1) psum += __shfl_xor(psum, off);
            lrun[r] = lrun[r] * corr + psum;
            #pragma unroll
            for (int nb = 0; nb < 4; ++nb) oacc[nb][r] *= corr;
            mrun[r] = mnew;
        }

        // P: C-layout -> LDS -> A-layout (per-wave buffer, no cross-wave barrier needed)
        #pragma unroll
        for (int nb = 0; nb < 4; ++nb)
            #pragma unroll
            for (int r = 0; r < 4; ++r)
                Psm[wid][g * 4 + r][nb * 16 + r16] = (_Float16)p[nb][r];

        f16x8 pa0 = *(const f16x8*)&Psm[wid][r16][g * 8];
        f16x8 pa1 = *(const f16x8*)&Psm[wid][r16][32 + g * 8];

        // O += P V   (B-operand = V[key][dim] = Vsm[dim][key])
        #pragma unroll
        for (int nb = 0; nb < 4; ++nb) {
            f16x8 vb0 = *(const f16x8*)&Vsm[nb * 16 + r16][g * 8];
            f16x8 vb1 = *(const f16x8*)&Vsm[nb * 16 + r16][32 + g * 8];
            oacc[nb] = __builtin_amdgcn_mfma_f32_16x16x32_f16(pa0, vb0, oacc[nb], 0, 0, 0);
            oacc[nb] = __builtin_amdgcn_mfma_f32_16x16x32_f16(pa1, vb1, oacc[nb], 0, 0, 0);
        }
    }

    const int b = bh >> 4, h = bh & 15;
    #pragma unroll
    for (int nb = 0; nb < 4; ++nb)
        #pragma unroll
        for (int r = 0; r < 4; ++r) {
            int row = t0 + wid * 16 + g * 4 + r;
            y[((long)(b * T_SEQ + row)) * D_MODEL + h * HD + nb * 16 + r16] = oacc[nb][r] / lrun[r];
        }
}

// ---------------- launch ----------------
extern "C" void kernel_launch(void* const* d_in, const int* in_sizes, int n_in,
                              void* d_out, int out_size, void* d_ws, size_t ws_size,
                              hipStream_t stream) {
    const float* x  = (const float*)d_in[0];
    const float* Wq = (const float*)d_in[1];
    const float* bq = (const float*)d_in[2];
    const float* Wk = (const float*)d_in[3];
    const float* bk = (const float*)d_in[4];
    const float* Wv = (const float*)d_in[5];
    const float* bv = (const float*)d_in[6];
    const float* Wo = (const float*)d_in[7];
    const float* bo = (const float*)d_in[8];

    char* ws = (char*)d_ws;
    unsigned int* amax = (unsigned int*)ws;                     // 256 B
    _Float16* xq  = (_Float16*)(ws + 256);                      // 8 MB
    _Float16* wqh = (_Float16*)(ws + 256 + 8388608L);           // 2 MB each
    _Float16* wkh = (_Float16*)(ws + 256 + 8388608L + 2097152L);
    _Float16* wvh = (_Float16*)(ws + 256 + 8388608L + 2L * 2097152L);
    _Float16* woh = (_Float16*)(ws + 256 + 8388608L + 3L * 2097152L);
    char* p2 = ws + 256 + 8388608L + 4L * 2097152L;
    _Float16* qh  = (_Float16*)p2;                              // 8 MB each (f16)
    _Float16* kh  = (_Float16*)(p2 + 8388608L);
    _Float16* vh  = (_Float16*)(p2 + 2L * 8388608L);
    _Float16* vth = (_Float16*)(p2 + 3L * 8388608L);
    float*    yb  = (float*)(p2 + 4L * 8388608L);               // 16 MB fp32
    _Float16* yq  = (_Float16*)(p2 + 4L * 8388608L + 16777216L);// 8 MB

    const long NX4 = (long)NB * T_SEQ * D_MODEL / 4;   // 1048576
    const long NW4 = (long)D_MODEL * D_MODEL / 4;      // 262144

    k_init<<<1, 64, 0, stream>>>(amax);
    k_absmax<<<1024, 256, 0, stream>>>(x,  NX4, amax + 0);
    k_absmax<<<512,  256, 0, stream>>>(Wq, NW4, amax + 1);
    k_absmax<<<512,  256, 0, stream>>>(Wk, NW4, amax + 2);
    k_absmax<<<512,  256, 0, stream>>>(Wv, NW4, amax + 3);
    k_absmax<<<512,  256, 0, stream>>>(Wo, NW4, amax + 4);

    k_quant<<<1024, 256, 0, stream>>>(x,  xq,  amax + 0, NX4);
    k_quant<<<512,  256, 0, stream>>>(Wq, wqh, amax + 1, NW4);
    k_quant<<<512,  256, 0, stream>>>(Wk, wkh, amax + 2, NW4);
    k_quant<<<512,  256, 0, stream>>>(Wv, wvh, amax + 3, NW4);
    k_quant<<<512,  256, 0, stream>>>(Wo, woh, amax + 4, NW4);

    dim3 ggrid(8, 32);
    k_gemm<2><<<ggrid, 256, 0, stream>>>(xq, wqh, bq, amax + 0, amax + 1, qh);
    k_gemm<2><<<ggrid, 256, 0, stream>>>(xq, wkh, bk, amax + 0, amax + 2, kh);
    k_gemm<2><<<ggrid, 256, 0, stream>>>(xq, wvh, bv, amax + 0, amax + 3, vh);

    k_vtrans<<<dim3(T_SEQ / 64, NB * NH), 256, 0, stream>>>(vh, vth);

    k_attn<<<dim3(T_SEQ / 64, NB * NH), 256, 0, stream>>>(qh, kh, vth, yb);

    k_absmax<<<1024, 256, 0, stream>>>(yb, NX4, amax + 5);
    k_quant<<<1024, 256, 0, stream>>>(yb, yq, amax + 5, NX4);
    k_gemm<0><<<ggrid, 256, 0, stream>>>(yq, woh, bo, amax + 5, amax + 4, (void*)d_out);
}

// Round 3
// 224.188 us; speedup vs baseline: 6.6716x; 2.0050x over previous
//
#include <hip/hip_runtime.h>
#include <hip/hip_fp16.h>

#define T_SEQ 2048
#define D_MODEL 1024
#define NB 2
#define NH 16
#define HD 64

using f16x8 = __attribute__((ext_vector_type(8))) _Float16;
using f16x4 = __attribute__((ext_vector_type(4))) _Float16;
using f32x4 = __attribute__((ext_vector_type(4))) float;

__device__ __forceinline__ void gload_lds16(const void* g, void* l) {
    __builtin_amdgcn_global_load_lds((const __attribute__((address_space(1))) void*)g,
                                     (__attribute__((address_space(3))) void*)l, 16, 0, 0);
}

__global__ void k_init(unsigned int* amax) { if (threadIdx.x < 8) amax[threadIdx.x] = 0u; }

// ---------- absmax: y<4 -> x slice y (slot 0); y>=4 -> W[y-4] (slot 1+y-4) ----------
__global__ __launch_bounds__(256)
void k_absmax8(const float* __restrict__ x,
               const float* __restrict__ w0, const float* __restrict__ w1,
               const float* __restrict__ w2, const float* __restrict__ w3,
               unsigned int* __restrict__ amax) {
    const int y = blockIdx.y;
    const float* p; int slot;
    if (y < 4) { p = x + (long)y * 1048576; slot = 0; }
    else { int w = y - 4; p = (w == 0) ? w0 : (w == 1) ? w1 : (w == 2) ? w2 : w3; slot = 1 + w; }
    const long n4 = 262144;
    long i = (long)blockIdx.x * blockDim.x + threadIdx.x;
    const long stride = (long)gridDim.x * blockDim.x;
    float m = 0.f;
    for (; i < n4; i += stride) {
        float4 v = ((const float4*)p)[i];
        m = fmaxf(fmaxf(fmaxf(fabsf(v.x), fabsf(v.y)), fmaxf(fabsf(v.z), fabsf(v.w))), m);
    }
    #pragma unroll
    for (int off = 32; off; off >>= 1) m = fmaxf(m, __shfl_xor(m, off));
    if ((threadIdx.x & 63) == 0 && m > 0.f) atomicMax(amax + slot, __float_as_uint(m));
}

// ---------- quantize to integer codes (f16): same y decode as k_absmax8 ----------
__global__ __launch_bounds__(256)
void k_quant8(const float* __restrict__ x,
              const float* __restrict__ w0, const float* __restrict__ w1,
              const float* __restrict__ w2, const float* __restrict__ w3,
              _Float16* __restrict__ xq,
              _Float16* __restrict__ o0, _Float16* __restrict__ o1,
              _Float16* __restrict__ o2, _Float16* __restrict__ o3,
              const unsigned int* __restrict__ amax) {
    const int y = blockIdx.y;
    const float* p; _Float16* o; int slot;
    if (y < 4) { p = x + (long)y * 1048576; o = xq + (long)y * 1048576; slot = 0; }
    else {
        int w = y - 4;
        p = (w == 0) ? w0 : (w == 1) ? w1 : (w == 2) ? w2 : w3;
        o = (w == 0) ? o0 : (w == 1) ? o1 : (w == 2) ? o2 : o3;
        slot = 1 + w;
    }
    float scale = fmaxf(__uint_as_float(amax[slot]) / 127.0f, 1e-8f);
    const long n4 = 262144;
    long i = (long)blockIdx.x * blockDim.x + threadIdx.x;
    const long stride = (long)gridDim.x * blockDim.x;
    for (; i < n4; i += stride) {
        float4 v = ((const float4*)p)[i];
        f16x4 q;
        q[0] = (_Float16)fminf(127.f, fmaxf(-128.f, rintf(v.x / scale)));
        q[1] = (_Float16)fminf(127.f, fmaxf(-128.f, rintf(v.y / scale)));
        q[2] = (_Float16)fminf(127.f, fmaxf(-128.f, rintf(v.z / scale)));
        q[3] = (_Float16)fminf(127.f, fmaxf(-128.f, rintf(v.w / scale)));
        ((f16x4*)o)[i] = q;
    }
}

// plain quant for y buffer
__global__ __launch_bounds__(256)
void k_quant(const float* __restrict__ in, _Float16* __restrict__ out,
             const unsigned int* __restrict__ amax, long n4) {
    float scale = fmaxf(__uint_as_float(*amax) / 127.0f, 1e-8f);
    long i = (long)blockIdx.x * blockDim.x + threadIdx.x;
    const long stride = (long)gridDim.x * blockDim.x;
    for (; i < n4; i += stride) {
        float4 v = ((const float4*)in)[i];
        f16x4 q;
        q[0] = (_Float16)fminf(127.f, fmaxf(-128.f, rintf(v.x / scale)));
        q[1] = (_Float16)fminf(127.f, fmaxf(-128.f, rintf(v.y / scale)));
        q[2] = (_Float16)fminf(127.f, fmaxf(-128.f, rintf(v.z / scale)));
        q[3] = (_Float16)fminf(127.f, fmaxf(-128.f, rintf(v.w / scale)));
        ((f16x4*)out)[i] = q;
    }
}

// ---------- shared GEMM core: 128x128 tile, K=1024, codes @ codes^T ----------
__device__ __forceinline__ void gemm_core(const _Float16* __restrict__ A,
                                          const _Float16* __restrict__ Bw,
                                          int m0, int n0, int tid, f32x4 (&acc)[4][4]) {
    __shared__ _Float16 Asm[128 * 32];
    __shared__ _Float16 Bsm[128 * 32];
    const int lane = tid & 63, wid = tid >> 6;
    const int r16 = lane & 15, g = lane >> 4;
    const int wr = wid >> 1, wc = wid & 1;
    #pragma unroll
    for (int m = 0; m < 4; ++m)
        #pragma unroll
        for (int n = 0; n < 4; ++n) acc[m][n] = (f32x4){0.f, 0.f, 0.f, 0.f};
    for (int kt = 0; kt < 1024; kt += 32) {
        __syncthreads();
        #pragma unroll
        for (int s2 = 0; s2 < 2; ++s2) {
            int c = tid + s2 * 256;
            int row = c >> 2, cb = (c & 3) * 8;
            gload_lds16(&A[(long)(m0 + row) * 1024 + kt + cb], &Asm[c * 8]);
            gload_lds16(&Bw[(long)(n0 + row) * 1024 + kt + cb], &Bsm[c * 8]);
        }
        __syncthreads();
        f16x8 af[4], bf[4];
        #pragma unroll
        for (int m = 0; m < 4; ++m)
            af[m] = *(const f16x8*)&Asm[(wr * 64 + m * 16 + r16) * 32 + g * 8];
        #pragma unroll
        for (int n = 0; n < 4; ++n)
            bf[n] = *(const f16x8*)&Bsm[(wc * 64 + n * 16 + r16) * 32 + g * 8];
        #pragma unroll
        for (int m = 0; m < 4; ++m)
            #pragma unroll
            for (int n = 0; n < 4; ++n)
                acc[m][n] = __builtin_amdgcn_mfma_f32_16x16x32_f16(af[m], bf[n], acc[m][n], 0, 0, 0);
    }
}

// ---------- fused QKV projection; z=0->q, z=1->k (both [bh][t][d] f16), z=2->v^T [bh][d][t] ----------
__global__ __launch_bounds__(256)
void k_gemm_qkv(const _Float16* __restrict__ A,
                const _Float16* __restrict__ wq, const _Float16* __restrict__ wk,
                const _Float16* __restrict__ wv,
                const float* __restrict__ bq, const float* __restrict__ bk,
                const float* __restrict__ bv,
                const unsigned int* __restrict__ amax,
                _Float16* __restrict__ qo, _Float16* __restrict__ ko,
                _Float16* __restrict__ vto) {
    const int z = blockIdx.z;
    const _Float16* Bw = (z == 0) ? wq : (z == 1) ? wk : wv;
    const float* bias = (z == 0) ? bq : (z == 1) ? bk : bv;
    const int tid = threadIdx.x;
    const int m0 = blockIdx.y * 128, n0 = blockIdx.x * 128;
    const int lane = tid & 63, wid = tid >> 6;
    const int r16 = lane & 15, g = lane >> 4;
    const int wr = wid >> 1, wc = wid & 1;

    f32x4 acc[4][4];
    gemm_core(A, Bw, m0, n0, tid, acc);

    float sA = fmaxf(__uint_as_float(amax[0]) / 127.0f, 1e-8f);
    float sB = fmaxf(__uint_as_float(amax[1 + z]) / 127.0f, 1e-8f);
    float s = sA * sB;
    if (z < 2) {
        _Float16* out = (z == 0) ? qo : ko;
        #pragma unroll
        for (int m = 0; m < 4; ++m)
            #pragma unroll
            for (int n = 0; n < 4; ++n) {
                int col = n0 + wc * 64 + n * 16 + r16;
                float bcol = bias[col];
                int h = col >> 6, d = col & 63;
                #pragma unroll
                for (int r = 0; r < 4; ++r) {
                    int row = m0 + wr * 64 + m * 16 + g * 4 + r;
                    int b = row >> 11, t = row & 2047;
                    out[(((long)(b * NH + h)) * T_SEQ + t) * HD + d] =
                        (_Float16)(acc[m][n][r] * s + bcol);
                }
            }
    } else {
        #pragma unroll
        for (int m = 0; m < 4; ++m)
            #pragma unroll
            for (int n = 0; n < 4; ++n) {
                int col = n0 + wc * 64 + n * 16 + r16;
                float bcol = bias[col];
                int h = col >> 6, d = col & 63;
                int row0 = m0 + wr * 64 + m * 16 + g * 4;
                int b = row0 >> 11, t = row0 & 2047;
                f16x4 pk;
                #pragma unroll
                for (int r = 0; r < 4; ++r) pk[r] = (_Float16)(acc[m][n][r] * s + bcol);
                *(f16x4*)&vto[(((long)(b * NH + h)) * HD + d) * T_SEQ + t] = pk;
            }
    }
}

// ---------- output projection GEMM -> fp32 d_out ----------
__global__ __launch_bounds__(256)
void k_gemm_o(const _Float16* __restrict__ A, const _Float16* __restrict__ Bw,
              const float* __restrict__ bias,
              const unsigned int* __restrict__ amaxA, const unsigned int* __restrict__ amaxB,
              float* __restrict__ out) {
    const int tid = threadIdx.x;
    const int m0 = blockIdx.y * 128, n0 = blockIdx.x * 128;
    const int lane = tid & 63, wid = tid >> 6;
    const int r16 = lane & 15, g = lane >> 4;
    const int wr = wid >> 1, wc = wid & 1;

    f32x4 acc[4][4];
    gemm_core(A, Bw, m0, n0, tid, acc);

    float sA = fmaxf(__uint_as_float(*amaxA) / 127.0f, 1e-8f);
    float sB = fmaxf(__uint_as_float(*amaxB) / 127.0f, 1e-8f);
    float s = sA * sB;
    #pragma unroll
    for (int m = 0; m < 4; ++m)
        #pragma unroll
        for (int n = 0; n < 4; ++n) {
            int col = n0 + wc * 64 + n * 16 + r16;
            float bcol = bias[col];
            #pragma unroll
            for (int r = 0; r < 4; ++r) {
                int row = m0 + wr * 64 + m * 16 + g * 4 + r;
                out[(long)row * 1024 + col] = acc[m][n][r] * s + bcol;
            }
        }
}

// ---------- flash attention: balanced Q-tile pairs, double-buffered K/V, defer-max ----------
// q,k: f16 [bh][t][64]; vt: f16 [bh][64][t]; y: fp32 [B][T][1024]; folds absmax(y) -> amax5
__global__ __launch_bounds__(256)
void k_attn(const _Float16* __restrict__ q, const _Float16* __restrict__ kk,
            const _Float16* __restrict__ vt, float* __restrict__ y,
            unsigned int* __restrict__ amax5) {
    __shared__ _Float16 Kd[2][4096];       // [64][64] linear, chunk-XOR swizzled
    __shared__ _Float16 Vd[2][4096];
    __shared__ _Float16 Psm[4][16][72];    // per-wave P round-trip

    const int bh = blockIdx.y, jb = blockIdx.x;
    const int tid = threadIdx.x, wid = tid >> 6, lane = tid & 63;
    const int r16 = lane & 15, g = lane >> 4;
    const long base = (long)bh * T_SEQ * HD;
    const long vbase = (long)bh * HD * T_SEQ;
    const int b = bh >> 4, h = bh & 15;
    float bmax = 0.f;

    auto STAGE = [&](int jt, int buf) {
        const _Float16* kp = kk + base + (long)jt * 64 * HD;
        const _Float16* vp = vt + vbase + jt * 64;
        #pragma unroll
        for (int s2 = 0; s2 < 2; ++s2) {
            int slot = tid + s2 * 256;           // linear LDS chunk (dest = base + lane*16)
            int row = slot >> 3;
            int ch = (slot & 7) ^ (row & 7);     // pre-swizzled global source chunk
            gload_lds16(kp + row * HD + ch * 8, &Kd[buf][slot * 8]);
            gload_lds16(vp + (long)row * T_SEQ + ch * 8, &Vd[buf][slot * 8]);
        }
    };

    #pragma unroll 1
    for (int sub = 0; sub < 2; ++sub) {
        const int J = sub ? jb : (31 - jb);      // heavy tile first; total 33 steps/block
        const int t0 = J * 64;
        const int nkt = J + 1;

        f16x8 qf0, qf1;
        {
            const _Float16* qp = q + base + (long)(t0 + wid * 16 + r16) * HD + g * 8;
            qf0 = *(const f16x8*)qp;
            qf1 = *(const f16x8*)(qp + 32);
            #pragma unroll
            for (int u = 0; u < 8; ++u) { qf0[u] *= (_Float16)0.125f; qf1[u] *= (_Float16)0.125f; }
        }
        float mrun = -INFINITY;
        float lacc[4] = {0.f, 0.f, 0.f, 0.f};
        f32x4 oacc[4];
        #pragma unroll
        for (int nb = 0; nb < 4; ++nb) oacc[nb] = (f32x4){0.f, 0.f, 0.f, 0.f};

        __syncthreads();                         // all waves done with prev buffers
        STAGE(0, 0);
        int cur = 0;
        for (int jt = 0; jt < nkt; ++jt) {
            __syncthreads();                     // drains vmcnt: buf[cur] ready
            if (jt + 1 < nkt) STAGE(jt + 1, cur ^ 1);   // prefetch under compute

            const _Float16* Kc = &Kd[cur][0];
            const _Float16* Vc = &Vd[cur][0];
            f32x4 s[4];
            #pragma unroll
            for (int nb = 0; nb < 4; ++nb) {
                int row = nb * 16 + r16;
                f16x8 kb0 = *(const f16x8*)&Kc[row * 64 + (((g)     ^ (row & 7)) << 3)];
                f16x8 kb1 = *(const f16x8*)&Kc[row * 64 + (((4 + g) ^ (row & 7)) << 3)];
                f32x4 a = (f32x4){0.f, 0.f, 0.f, 0.f};
                a = __builtin_amdgcn_mfma_f32_16x16x32_f16(qf0, kb0, a, 0, 0, 0);
                a = __builtin_amdgcn_mfma_f32_16x16x32_f16(qf1, kb1, a, 0, 0, 0);
                s[nb] = a;
            }
            if (jt == J) {                       // diagonal: causal mask
                #pragma unroll
                for (int nb = 0; nb < 4; ++nb)
                    #pragma unroll
                    for (int r = 0; r < 4; ++r)
                        if (nb * 16 + r16 > wid * 16 + g * 4 + r) s[nb][r] = -INFINITY;
            }
            // wave-uniform tile max + deferred rescale (THR=8; p <= e^8 fits f16)
            float M = s[0][0];
            #pragma unroll
            for (int nb = 0; nb < 4; ++nb)
                #pragma unroll
                for (int r = 0; r < 4; ++r) M = fmaxf(M, s[nb][r]);
            #pragma unroll
            for (int off = 1; off < 64; off <<= 1) M = fmaxf(M, __shfl_xor(M, off));
            if (M > mrun + 8.f) {
                float corr = __expf(mrun - M);   // first tile: exp(-inf)=0
                #pragma unroll
                for (int r = 0; r < 4; ++r) lacc[r] *= corr;
                #pragma unroll
                for (int nb = 0; nb < 4; ++nb)
                    #pragma unroll
                    for (int r = 0; r < 4; ++r) oacc[nb][r] *= corr;
                mrun = M;
            }
            #pragma unroll
            for (int nb = 0; nb < 4; ++nb)
                #pragma unroll
                for (int r = 0; r < 4; ++r) {
                    float p = __expf(s[nb][r] - mrun);
                    lacc[r] += p;                // per-lane deferred l; reduced once at end
                    Psm[wid][g * 4 + r][nb * 16 + r16] = (_Float16)p;
                }
            f16x8 pa0 = *(const f16x8*)&Psm[wid][r16][g * 8];
            f16x8 pa1 = *(const f16x8*)&Psm[wid][r16][32 + g * 8];
            #pragma unroll
            for (int nb = 0; nb < 4; ++nb) {
                int row = nb * 16 + r16;
                f16x8 vb0 = *(const f16x8*)&Vc[row * 64 + (((g)     ^ (row & 7)) << 3)];
                f16x8 vb1 = *(const f16x8*)&Vc[row * 64 + (((4 + g) ^ (row & 7)) << 3)];
                oacc[nb] = __builtin_amdgcn_mfma_f32_16x16x32_f16(pa0, vb0, oacc[nb], 0, 0, 0);
                oacc[nb] = __builtin_amdgcn_mfma_f32_16x16x32_f16(pa1, vb1, oacc[nb], 0, 0, 0);
            }
            cur ^= 1;
        }
        // epilogue: reduce row sums once, write y, fold absmax
        float lsum[4];
        #pragma unroll
        for (int r = 0; r < 4; ++r) {
            float L = lacc[r];
            #pragma unroll
            for (int off = 1; off < 16; off <<= 1) L += __shfl_xor(L, off);
            lsum[r] = L;
        }
        #pragma unroll
        for (int nb = 0; nb < 4; ++nb)
            #pragma unroll
            for (int r = 0; r < 4; ++r) {
                float val = oacc[nb][r] / lsum[r];
                bmax = fmaxf(bmax, fabsf(val));
                y[((long)(b * T_SEQ + t0 + wid * 16 + g * 4 + r)) * D_MODEL + h * HD + nb * 16 + r16] = val;
            }
    }
    #pragma unroll
    for (int off = 1; off < 64; off <<= 1) bmax = fmaxf(bmax, __shfl_xor(bmax, off));
    if (lane == 0 && bmax > 0.f) atomicMax(amax5, __float_as_uint(bmax));
}

// ---------------- launch ----------------
extern "C" void kernel_launch(void* const* d_in, const int* in_sizes, int n_in,
                              void* d_out, int out_size, void* d_ws, size_t ws_size,
                              hipStream_t stream) {
    const float* x  = (const float*)d_in[0];
    const float* Wq = (const float*)d_in[1];
    const float* bq = (const float*)d_in[2];
    const float* Wk = (const float*)d_in[3];
    const float* bk = (const float*)d_in[4];
    const float* Wv = (const float*)d_in[5];
    const float* bv = (const float*)d_in[6];
    const float* Wo = (const float*)d_in[7];
    const float* bo = (const float*)d_in[8];

    char* ws = (char*)d_ws;
    unsigned int* amax = (unsigned int*)ws;                     // 256 B
    _Float16* xq  = (_Float16*)(ws + 256);                      // 8 MB
    _Float16* wqh = (_Float16*)(ws + 256 + 8388608L);           // 2 MB each
    _Float16* wkh = (_Float16*)(ws + 256 + 8388608L + 2097152L);
    _Float16* wvh = (_Float16*)(ws + 256 + 8388608L + 2L * 2097152L);
    _Float16* woh = (_Float16*)(ws + 256 + 8388608L + 3L * 2097152L);
    char* p2 = ws + 256 + 8388608L + 4L * 2097152L;
    _Float16* qh  = (_Float16*)p2;                              // 8 MB each
    _Float16* kh  = (_Float16*)(p2 + 8388608L);
    _Float16* vth = (_Float16*)(p2 + 2L * 8388608L);
    float*    yb  = (float*)(p2 + 3L * 8388608L);               // 16 MB fp32
    _Float16* yq  = (_Float16*)(p2 + 3L * 8388608L + 16777216L);// 8 MB

    const long NX4 = (long)NB * T_SEQ * D_MODEL / 4;            // 1048576

    k_init<<<1, 64, 0, stream>>>(amax);
    k_absmax8<<<dim3(128, 8), 256, 0, stream>>>(x, Wq, Wk, Wv, Wo, amax);
    k_quant8<<<dim3(128, 8), 256, 0, stream>>>(x, Wq, Wk, Wv, Wo,
                                               xq, wqh, wkh, wvh, woh, amax);
    k_gemm_qkv<<<dim3(8, 32, 3), 256, 0, stream>>>(xq, wqh, wkh, wvh, bq, bk, bv,
                                                   amax, qh, kh, vth);
    k_attn<<<dim3(16, 32), 256, 0, stream>>>(qh, kh, vth, yb, amax + 5);
    k_quant<<<1024, 256, 0, stream>>>(yb, yq, amax + 5, NX4);
    k_gemm_o<<<dim3(8, 32), 256, 0, stream>>>(yq, woh, bo, amax + 5, amax + 4, (float*)d_out);
}